// Round 21
// baseline (259.777 us; speedup 1.0000x reference)
//
#include <hip/hip_runtime.h>
#include <hip/hip_bf16.h>
#include <stdint.h>

typedef __attribute__((ext_vector_type(8))) short short8v;     // 8 x bf16 (MFMA A/B frag)
typedef __attribute__((ext_vector_type(4))) float float4v;     // MFMA C/D frag / vec loads
typedef __attribute__((ext_vector_type(4))) unsigned short ushort4v;
typedef __attribute__((ext_vector_type(4))) unsigned int uint4v;

#define FINF __builtin_huge_valf()
#define BB 64
#define NN 512
#define DD 256
#define TT_SKEW 640   // skew rows: tau = r + 2*(j>>3) in [0, 511+126] -> pad to 640

// ws layout (bytes):
//   [0,        16777216)  xnb bf16 [B][N][D]
//   [16777216, 33554432)  ynb bf16 [B][N][D]
//   [33554432, 75497472)  cost_skew bf16 [B][640][512] (cell (r,j) at row tau=r+2*(j>>3), col j)
//   [75497472, 75628544)  colsum f32 [B][512]

static __device__ __forceinline__ unsigned short f2bf(float f) {
  union { float f; uint32_t u; } a; a.f = f;
  uint32_t r = a.u + 0x7fffu + ((a.u >> 16) & 1u);   // RNE
  return (unsigned short)(r >> 16);
}
static __device__ __forceinline__ float bf2f(uint16_t v) {
  return __uint_as_float(((uint32_t)v) << 16);
}

// Lane shift-by-1 WITHOUT the DS pipe: DPP row_shr:1 (lane i <- i-1 within
// each 16-lane row; lanes 0/16/32/48 get 0 via bound_ctrl) + readlane +
// v_writelane_b32 (inline asm; builtin absent on this toolchain) patches for
// the row-crossing lanes 16/32/48. Lane 0's result is garbage(0) but every
// use overrides lane 0 via the is0 select. Pure VALU/SALU: ~20 cy chain vs
// ds_bpermute's ~120+ cy DS round trip.
static __device__ __forceinline__ float shift_up1(float x) {
  const uint32_t xi = __float_as_uint(x);
  uint32_t r = __builtin_amdgcn_update_dpp(0u, xi, 0x111, 0xf, 0xf, true); // row_shr:1
  const uint32_t s15 = __builtin_amdgcn_readlane(xi, 15);
  const uint32_t s31 = __builtin_amdgcn_readlane(xi, 31);
  const uint32_t s47 = __builtin_amdgcn_readlane(xi, 47);
  asm("v_writelane_b32 %0, %1, 16" : "+v"(r) : "s"(s15));
  asm("v_writelane_b32 %0, %1, 32" : "+v"(r) : "s"(s31));
  asm("v_writelane_b32 %0, %1, 48" : "+v"(r) : "s"(s47));
  return __uint_as_float(r);
}

// ---------------- Kernel 0: zero the colsum buffer ----------------
__global__ __launch_bounds__(256) void zero_colsum_kernel(float* __restrict__ colsum)
{
  colsum[blockIdx.x * 256 + threadIdx.x] = 0.0f;
}

// ---------------- Kernel 1: row-normalize + cast to bf16 ----------------
__global__ __launch_bounds__(256) void norm_cast_kernel(
    const float* __restrict__ x, const float* __restrict__ y,
    uint16_t* __restrict__ xnb, uint16_t* __restrict__ ynb)
{
  const int wave = threadIdx.x >> 6, lane = threadIdx.x & 63;
  const int row = blockIdx.x * 4 + wave;
  const float* src; uint16_t* dst;
  if (row < BB * NN) { src = x + (size_t)row * DD;            dst = xnb + (size_t)row * DD; }
  else               { src = y + (size_t)(row - BB*NN) * DD;  dst = ynb + (size_t)(row - BB*NN) * DD; }
  const float4v v = *(const float4v*)(src + lane * 4);
  float s = v[0]*v[0] + v[1]*v[1] + v[2]*v[2] + v[3]*v[3];
  #pragma unroll
  for (int d = 1; d < 64; d <<= 1) s += __shfl_xor(s, d, 64);
  const float inv = 1.0f / fmaxf(sqrtf(s), 1e-8f);
  ushort4v o;
  o[0] = f2bf(v[0] * inv); o[1] = f2bf(v[1] * inv);
  o[2] = f2bf(v[2] * inv); o[3] = f2bf(v[3] * inv);
  *(ushort4v*)(dst + lane * 4) = o;
}

// ---------------- Kernel 2: cost = 1 - xn·yn -> bf16 skew + colsum atomics ----------------
__global__ __launch_bounds__(256) void gemm_cost_kernel(
    const uint16_t* __restrict__ xnb, const uint16_t* __restrict__ ynb,
    uint16_t* __restrict__ skew, float* __restrict__ colsum)
{
  __shared__ uint16_t As[128 * 32];
  __shared__ uint16_t Bs[128 * 32];
  const int bid = blockIdx.x;
  const int b = bid >> 4, tm = (bid >> 2) & 3, tn = bid & 3;
  const int tid = threadIdx.x, wave = tid >> 6, lane = tid & 63;
  const int wr = wave >> 1, wc = wave & 1;

  const char* Ab = (const char*)(xnb + (size_t)b * NN * DD + (size_t)tm * 128 * DD);
  const char* Bb = (const char*)(ynb + (size_t)b * NN * DD + (size_t)tn * 128 * DD);

  float4v acc[4][4];
  #pragma unroll
  for (int i = 0; i < 4; i++)
    #pragma unroll
    for (int j = 0; j < 4; j++) acc[i][j] = (float4v){0.f, 0.f, 0.f, 0.f};

  const int seg0 = wave * 2;
  const int o0 = seg0 * 1024 + lane * 16;
  const int o1 = o0 + 1024;
  const int r0 = o0 >> 6, c0 = o0 & 63;
  const int r1 = o1 >> 6, c1 = o1 & 63;

  for (int kk = 0; kk < 8; kk++) {
    const int kb = kk * 64;
    __builtin_amdgcn_global_load_lds(
        (const __attribute__((address_space(1))) uint32_t*)(Ab + (size_t)r0 * 512 + kb + c0),
        (__attribute__((address_space(3))) uint32_t*)((char*)As + seg0 * 1024), 16, 0, 0);
    __builtin_amdgcn_global_load_lds(
        (const __attribute__((address_space(1))) uint32_t*)(Ab + (size_t)r1 * 512 + kb + c1),
        (__attribute__((address_space(3))) uint32_t*)((char*)As + (seg0 + 1) * 1024), 16, 0, 0);
    __builtin_amdgcn_global_load_lds(
        (const __attribute__((address_space(1))) uint32_t*)(Bb + (size_t)r0 * 512 + kb + c0),
        (__attribute__((address_space(3))) uint32_t*)((char*)Bs + seg0 * 1024), 16, 0, 0);
    __builtin_amdgcn_global_load_lds(
        (const __attribute__((address_space(1))) uint32_t*)(Bb + (size_t)r1 * 512 + kb + c1),
        (__attribute__((address_space(3))) uint32_t*)((char*)Bs + (seg0 + 1) * 1024), 16, 0, 0);
    __syncthreads();

    short8v af[4], bfr[4];
    #pragma unroll
    for (int mi = 0; mi < 4; mi++) {
      const int rr = wr * 64 + mi * 16 + (lane & 15);
      af[mi] = *(const short8v*)((const char*)As + rr * 64 + (lane >> 4) * 16);
    }
    #pragma unroll
    for (int nj = 0; nj < 4; nj++) {
      const int rr = wc * 64 + nj * 16 + (lane & 15);
      bfr[nj] = *(const short8v*)((const char*)Bs + rr * 64 + (lane >> 4) * 16);
    }
    #pragma unroll
    for (int mi = 0; mi < 4; mi++)
      #pragma unroll
      for (int nj = 0; nj < 4; nj++)
        acc[mi][nj] = __builtin_amdgcn_mfma_f32_16x16x32_bf16(af[mi], bfr[nj], acc[mi][nj], 0, 0, 0);
    __syncthreads();
  }

  uint16_t* Cb = skew + (size_t)b * TT_SKEW * NN;
  #pragma unroll
  for (int mi = 0; mi < 4; mi++)
    #pragma unroll
    for (int nj = 0; nj < 4; nj++) {
      const int cc = tn * 128 + wc * 64 + nj * 16 + (lane & 15);
      const int lg = cc >> 3;
      #pragma unroll
      for (int v = 0; v < 4; v++) {
        const int rr = tm * 128 + wr * 64 + mi * 16 + (lane >> 4) * 4 + v;
        Cb[(size_t)(rr + 2 * lg) * NN + cc] = f2bf(1.0f - acc[mi][nj][v]);
      }
    }

  // column-sum partials (for neg LSE)
  #pragma unroll
  for (int nj = 0; nj < 4; nj++) {
    const int cc = tn * 128 + wc * 64 + nj * 16 + (lane & 15);
    float s = 0.f;
    #pragma unroll
    for (int mi = 0; mi < 4; mi++)
      #pragma unroll
      for (int v = 0; v < 4; v++) s += 1.0f - acc[mi][nj][v];
    s += __shfl_xor(s, 16, 64);
    s += __shfl_xor(s, 32, 64);
    if (lane < 16) atomicAdd(&colsum[b * 512 + cc], s);
  }
}

// ---------------- Kernel 3: DTW forward + in-wave backtrack (R18 + DPP shift) ----
// 64 blocks x 1 wave — R18's PASSED kernel with ONE change: the two
// __shfl_up (ds_bpermute, ~120cy DS round trip) are replaced by shift_up1
// (DPP row_shr:1 + readlane/writelane patches, pure VALU ~20cy). Lane 0's
// shift result is overridden by the is0 select in every use, exactly as the
// shfl result was. All other code byte-identical to R18.
__global__ __launch_bounds__(64, 1) void dtw_fwdbt_kernel(
    const uint16_t* __restrict__ skew, const float* __restrict__ colsum,
    float* __restrict__ out)
{
  extern __shared__ char lds_raw[];
  const int l = threadIdx.x;
  const int b = blockIdx.x;
  const uint16_t* csk = skew + (size_t)b * TT_SKEW * NN;
  const uint64_t base = (uint64_t)(uintptr_t)csk;
  const bool is0 = (l == 0);
  const uint32_t voff_base = 16u * (uint32_t)l;
  const uint32_t dump_addr = 65536u + (((uint32_t)l) << 2);

  uint4v ringA[8], ringB[8];     // rows 2t (A) and 2t+1 (B)
  #pragma unroll
  for (int i = 0; i < 8; ++i) {
    const uint32_t voA = voff_base + ((uint32_t)(2 * i) << 10);
    const uint32_t voB = voA + 1024u;
    asm volatile("global_load_dwordx4 %0, %1, %2" : "=v"(ringA[i]) : "v"(voA), "s"(base));
    asm volatile("global_load_dwordx4 %0, %1, %2" : "=v"(ringB[i]) : "v"(voB), "s"(base));
  }

  float tp[8];
  #pragma unroll
  for (int c = 0; c < 8; ++c) tp[c] = FINF;
  float cl0 = FINF, cl1 = FINF, carry = FINF;

  for (int t0 = 0; t0 < 320; t0 += 8) {
    #pragma unroll
    for (int u = 0; u < 8; ++u) {
      const int t = t0 + u;
      float shA = shift_up1(cl0);   // tc[r0][8l-1]
      float shB = shift_up1(cl1);   // tc[r1][8l-1]
      if (is0) { shA = (t == 0) ? 0.0f : FINF; shB = FINF; }
      const float sh_p0 = carry;            // tc[r0-1][8l-1]
      carry = shB;
      const float shA1 = is0 ? FINF : shA;  // row1 diag col0 (INF at l=0)

      asm volatile("s_waitcnt vmcnt(14)" : "+v"(ringA[u]), "+v"(ringB[u]));
      const uint4v A = ringA[u];
      const uint4v Bv = ringB[u];

      const uint32_t rlane = (uint32_t)(t - l);
      const bool valid = rlane < 256u;

      // unpack both rows + prefix sums
      float ca[8], cbv[8], S0[8], S1[8];
      #pragma unroll
      for (int k = 0; k < 4; ++k) {
        ca[2*k]   = __uint_as_float(A[k] << 16);
        ca[2*k+1] = __uint_as_float(A[k] & 0xFFFF0000u);
        cbv[2*k]   = __uint_as_float(Bv[k] << 16);
        cbv[2*k+1] = __uint_as_float(Bv[k] & 0xFFFF0000u);
      }
      S0[0] = ca[0]; S1[0] = cbv[0];
      #pragma unroll
      for (int c = 1; c < 8; ++c) { S0[c] = S0[c-1] + ca[c]; S1[c] = S1[c-1] + cbv[c]; }

      // ---- row 0 ----
      float dcp0[8], mu0[8], w0[8], PW0[8], tn0[8];
      dcp0[0] = sh_p0;
      #pragma unroll
      for (int c = 1; c < 8; ++c) dcp0[c] = tp[c-1];
      #pragma unroll
      for (int c = 0; c < 8; ++c) mu0[c] = fminf(dcp0[c], tp[c]);
      w0[0] = mu0[0];
      #pragma unroll
      for (int c = 1; c < 8; ++c) w0[c] = mu0[c] - S0[c-1];
      PW0[0] = w0[0];
      #pragma unroll
      for (int c = 1; c < 8; ++c) PW0[c] = fminf(PW0[c-1], w0[c]);
      #pragma unroll
      for (int c = 0; c < 8; ++c) tn0[c] = fminf(PW0[c], shA) + S0[c];

      // ---- row 1 (chains on row 0 in-lane) ----
      float dcp1[8], mu1[8], w1[8], PW1[8], tn1[8];
      dcp1[0] = shA1;
      #pragma unroll
      for (int c = 1; c < 8; ++c) dcp1[c] = tn0[c-1];
      #pragma unroll
      for (int c = 0; c < 8; ++c) mu1[c] = fminf(dcp1[c], tn0[c]);
      w1[0] = mu1[0];
      #pragma unroll
      for (int c = 1; c < 8; ++c) w1[c] = mu1[c] - S1[c-1];
      PW1[0] = w1[0];
      #pragma unroll
      for (int c = 1; c < 8; ++c) PW1[c] = fminf(PW1[c-1], w1[c]);
      #pragma unroll
      for (int c = 0; c < 8; ++c) tn1[c] = fminf(PW1[c], shB) + S1[c];

      // ---- decisions (ref tie-break diag > up > left): dd=(lc<mu)?2:(up<dcp) ----
      uint32_t word = 0;
      {
        float lc0[8], lc1[8];
        lc0[0] = shA; lc1[0] = shB;
        #pragma unroll
        for (int c = 1; c < 8; ++c) { lc0[c] = tn0[c-1]; lc1[c] = tn1[c-1]; }
        #pragma unroll
        for (int c = 0; c < 8; ++c) {
          const uint32_t e0 = (tp[c] < dcp0[c]) ? 1u : 0u;
          const uint32_t d0 = (lc0[c] < mu0[c]) ? 2u : e0;
          const uint32_t e1 = (tn0[c] < dcp1[c]) ? 1u : 0u;
          const uint32_t d1 = (lc1[c] < mu1[c]) ? 2u : e1;
          word |= (d0 << (2 * c)) | (d1 << (16 + 2 * c));
        }
      }
      const uint32_t waddr = valid ? ((rlane << 8) + (((uint32_t)l) << 2)) : dump_addr;
      *(uint32_t*)(lds_raw + waddr) = word;

      #pragma unroll
      for (int c = 0; c < 8; ++c) tp[c] = valid ? tn1[c] : tp[c];
      cl0 = valid ? tn0[7] : cl0;
      cl1 = tp[7];

      // refill rows 2(t+8), 2(t+8)+1 (clamped; keeps exactly 16 in flight)
      {
        int rr = 2 * (t + 8); if (rr > 638) rr = 638;
        const uint32_t voA = voff_base + ((uint32_t)rr << 10);
        const uint32_t voB = voA + 1024u;
        asm volatile("global_load_dwordx4 %0, %1, %2" : "=v"(ringA[u]) : "v"(voA), "s"(base));
        asm volatile("global_load_dwordx4 %0, %1, %2" : "=v"(ringB[u]) : "v"(voB), "s"(base));
      }
    }
  }
  asm volatile("s_waitcnt vmcnt(0)" ::: "memory");
  __syncthreads();

  // ---------------- in-wave epilogue (R18 verbatim) ----------------
  uint16_t* rlo    = (uint16_t*)(lds_raw + 65792);
  uint16_t* rhi    = (uint16_t*)(lds_raw + 66816);
  float*    colpos = (float*)  (lds_raw + 67840);
  const uint32_t* dec32 = (const uint32_t*)lds_raw;

  for (int r = l; r < NN; r += 64) { rlo[r] = 1; rhi[r] = 0; colpos[r] = 0.0f; }

  // ---- neg = LSE over colsum[b][0..511] (computed by GEMM epilogue) ----
  const float* cs = colsum + (size_t)b * 512;
  float nv[8];
  float m = -FINF;
  #pragma unroll
  for (int k = 0; k < 8; ++k) { nv[k] = cs[l + 64 * k]; m = fmaxf(m, nv[k]); }
  #pragma unroll
  for (int d = 1; d < 64; d <<= 1) m = fmaxf(m, __shfl_xor(m, d, 64));
  float e = 0.f;
  #pragma unroll
  for (int k = 0; k < 8; ++k) e += expf(nv[k] - m);
  #pragma unroll
  for (int d = 1; d < 64; d <<= 1) e += __shfl_xor(e, d, 64);
  const float neg = m + logf(e);
  __syncthreads();

  // ---- backtrack (lane 0): R8's exact walk over the LDS dec array ----
  if (l == 0) {
    int i = NN - 1, j = NN - 1, hicur = NN - 1;
    int cidx = -1; uint32_t cw = 0;
    while (i > 0 && j > 0) {
      const int widx = (i >> 1) * 64 + (j >> 3);
      if (widx != cidx) { cw = dec32[widx]; cidx = widx; }
      const uint32_t dd = (cw >> (((i & 1) << 4) + ((j & 7) << 1))) & 3u;
      if (dd == 2u) { j--; }           // left: stay in row
      else {
        rlo[i] = (uint16_t)j; rhi[i] = (uint16_t)hicur;  // leave row i
        i--;
        if (dd == 0u) j--;             // diag also moves left
        hicur = j;                     // entry column of new row
      }
    }
    rlo[i] = (uint16_t)j; rhi[i] = (uint16_t)hicur;      // pending row at exit
  }
  __syncthreads();

  // ---- colpos: 8 rows per lane (2-row skew addressing) ----
  for (int r = l; r < NN; r += 64) {
    const int lo = rlo[r], hi = rhi[r];
    for (int j = lo; j <= hi; j++) {
      const float cv = bf2f(csk[(size_t)(r + 2 * (j >> 3)) * NN + j]);
      atomicAdd(&colpos[j], cv);
    }
  }
  if (l == 0 && rlo[0] != 0) atomicAdd(&colpos[0], bf2f(csk[0]));
  __syncthreads();

  // ---- pos = LSE over colpos[512] ----
  float mv[8];
  float mx2 = -FINF;
  #pragma unroll
  for (int k = 0; k < 8; k++) { mv[k] = colpos[l + 64 * k]; mx2 = fmaxf(mx2, mv[k]); }
  #pragma unroll
  for (int d = 1; d < 64; d <<= 1) mx2 = fmaxf(mx2, __shfl_xor(mx2, d, 64));
  float se2 = 0.f;
  #pragma unroll
  for (int k = 0; k < 8; k++) se2 += expf(mv[k] - mx2);
  #pragma unroll
  for (int d = 1; d < 64; d <<= 1) se2 += __shfl_xor(se2, d, 64);
  const float pos = mx2 + logf(se2);

  if (l == 0) out[b] = pos - neg;
}

extern "C" void kernel_launch(void* const* d_in, const int* in_sizes, int n_in,
                              void* d_out, int out_size, void* d_ws, size_t ws_size,
                              hipStream_t stream)
{
  (void)in_sizes; (void)n_in; (void)out_size; (void)ws_size;
  const float* x = (const float*)d_in[0];
  const float* y = (const float*)d_in[1];
  float* out = (float*)d_out;
  char* ws = (char*)d_ws;
  uint16_t* xnb   = (uint16_t*)ws;
  uint16_t* ynb   = (uint16_t*)(ws + (size_t)16777216);
  uint16_t* skew  = (uint16_t*)(ws + (size_t)33554432);
  float*   colsum = (float*)   (ws + (size_t)75497472);

  (void)hipFuncSetAttribute((const void*)dtw_fwdbt_kernel,
                            hipFuncAttributeMaxDynamicSharedMemorySize, 69888);

  zero_colsum_kernel<<<128, 256, 0, stream>>>(colsum);
  norm_cast_kernel<<<16384, 256, 0, stream>>>(x, y, xnb, ynb);
  gemm_cost_kernel<<<1024, 256, 0, stream>>>(xnb, ynb, skew, colsum);
  dtw_fwdbt_kernel<<<64, 64, 69888, stream>>>(skew, colsum, out);
}

// Round 22
// 251.457 us; speedup vs baseline: 1.0331x; 1.0331x over previous
//
#include <hip/hip_runtime.h>
#include <hip/hip_bf16.h>
#include <stdint.h>

typedef __attribute__((ext_vector_type(8))) short short8v;     // 8 x bf16 (MFMA A/B frag)
typedef __attribute__((ext_vector_type(4))) float float4v;     // MFMA C/D frag / vec loads
typedef __attribute__((ext_vector_type(4))) unsigned short ushort4v;
typedef __attribute__((ext_vector_type(4))) unsigned int uint4v;

#define FINF __builtin_huge_valf()
#define BB 64
#define NN 512
#define DD 256
#define TT_SKEW 640   // skew rows: tau = r + 2*(j>>3) in [0, 511+126] -> pad to 640

// ws layout (bytes):
//   [0,        16777216)  xnb bf16 [B][N][D]
//   [16777216, 33554432)  ynb bf16 [B][N][D]
//   [33554432, 75497472)  cost_skew bf16 [B][640][512] (cell (r,j) at row tau=r+2*(j>>3), col j)
//   [75497472, 75628544)  colsum f32 [B][512]

static __device__ __forceinline__ unsigned short f2bf(float f) {
  union { float f; uint32_t u; } a; a.f = f;
  uint32_t r = a.u + 0x7fffu + ((a.u >> 16) & 1u);   // RNE
  return (unsigned short)(r >> 16);
}
static __device__ __forceinline__ float bf2f(uint16_t v) {
  return __uint_as_float(((uint32_t)v) << 16);
}

// ---------------- Kernel 0: zero the colsum buffer ----------------
__global__ __launch_bounds__(256) void zero_colsum_kernel(float* __restrict__ colsum)
{
  colsum[blockIdx.x * 256 + threadIdx.x] = 0.0f;
}

// ---------------- Kernel 1: row-normalize + cast to bf16 ----------------
__global__ __launch_bounds__(256) void norm_cast_kernel(
    const float* __restrict__ x, const float* __restrict__ y,
    uint16_t* __restrict__ xnb, uint16_t* __restrict__ ynb)
{
  const int wave = threadIdx.x >> 6, lane = threadIdx.x & 63;
  const int row = blockIdx.x * 4 + wave;
  const float* src; uint16_t* dst;
  if (row < BB * NN) { src = x + (size_t)row * DD;            dst = xnb + (size_t)row * DD; }
  else               { src = y + (size_t)(row - BB*NN) * DD;  dst = ynb + (size_t)(row - BB*NN) * DD; }
  const float4v v = *(const float4v*)(src + lane * 4);
  float s = v[0]*v[0] + v[1]*v[1] + v[2]*v[2] + v[3]*v[3];
  #pragma unroll
  for (int d = 1; d < 64; d <<= 1) s += __shfl_xor(s, d, 64);
  const float inv = 1.0f / fmaxf(sqrtf(s), 1e-8f);
  ushort4v o;
  o[0] = f2bf(v[0] * inv); o[1] = f2bf(v[1] * inv);
  o[2] = f2bf(v[2] * inv); o[3] = f2bf(v[3] * inv);
  *(ushort4v*)(dst + lane * 4) = o;
}

// ---------------- Kernel 2: cost = 1 - xn·yn -> bf16 skew + colsum atomics ----------------
// R8's proven 2-row-skew gemm + R13's proven colsum epilogue.
__global__ __launch_bounds__(256) void gemm_cost_kernel(
    const uint16_t* __restrict__ xnb, const uint16_t* __restrict__ ynb,
    uint16_t* __restrict__ skew, float* __restrict__ colsum)
{
  __shared__ uint16_t As[128 * 32];
  __shared__ uint16_t Bs[128 * 32];
  const int bid = blockIdx.x;
  const int b = bid >> 4, tm = (bid >> 2) & 3, tn = bid & 3;
  const int tid = threadIdx.x, wave = tid >> 6, lane = tid & 63;
  const int wr = wave >> 1, wc = wave & 1;

  const char* Ab = (const char*)(xnb + (size_t)b * NN * DD + (size_t)tm * 128 * DD);
  const char* Bb = (const char*)(ynb + (size_t)b * NN * DD + (size_t)tn * 128 * DD);

  float4v acc[4][4];
  #pragma unroll
  for (int i = 0; i < 4; i++)
    #pragma unroll
    for (int j = 0; j < 4; j++) acc[i][j] = (float4v){0.f, 0.f, 0.f, 0.f};

  const int seg0 = wave * 2;
  const int o0 = seg0 * 1024 + lane * 16;
  const int o1 = o0 + 1024;
  const int r0 = o0 >> 6, c0 = o0 & 63;
  const int r1 = o1 >> 6, c1 = o1 & 63;

  for (int kk = 0; kk < 8; kk++) {
    const int kb = kk * 64;
    __builtin_amdgcn_global_load_lds(
        (const __attribute__((address_space(1))) uint32_t*)(Ab + (size_t)r0 * 512 + kb + c0),
        (__attribute__((address_space(3))) uint32_t*)((char*)As + seg0 * 1024), 16, 0, 0);
    __builtin_amdgcn_global_load_lds(
        (const __attribute__((address_space(1))) uint32_t*)(Ab + (size_t)r1 * 512 + kb + c1),
        (__attribute__((address_space(3))) uint32_t*)((char*)As + (seg0 + 1) * 1024), 16, 0, 0);
    __builtin_amdgcn_global_load_lds(
        (const __attribute__((address_space(1))) uint32_t*)(Bb + (size_t)r0 * 512 + kb + c0),
        (__attribute__((address_space(3))) uint32_t*)((char*)Bs + seg0 * 1024), 16, 0, 0);
    __builtin_amdgcn_global_load_lds(
        (const __attribute__((address_space(1))) uint32_t*)(Bb + (size_t)r1 * 512 + kb + c1),
        (__attribute__((address_space(3))) uint32_t*)((char*)Bs + (seg0 + 1) * 1024), 16, 0, 0);
    __syncthreads();

    short8v af[4], bfr[4];
    #pragma unroll
    for (int mi = 0; mi < 4; mi++) {
      const int rr = wr * 64 + mi * 16 + (lane & 15);
      af[mi] = *(const short8v*)((const char*)As + rr * 64 + (lane >> 4) * 16);
    }
    #pragma unroll
    for (int nj = 0; nj < 4; nj++) {
      const int rr = wc * 64 + nj * 16 + (lane & 15);
      bfr[nj] = *(const short8v*)((const char*)Bs + rr * 64 + (lane >> 4) * 16);
    }
    #pragma unroll
    for (int mi = 0; mi < 4; mi++)
      #pragma unroll
      for (int nj = 0; nj < 4; nj++)
        acc[mi][nj] = __builtin_amdgcn_mfma_f32_16x16x32_bf16(af[mi], bfr[nj], acc[mi][nj], 0, 0, 0);
    __syncthreads();
  }

  uint16_t* Cb = skew + (size_t)b * TT_SKEW * NN;
  #pragma unroll
  for (int mi = 0; mi < 4; mi++)
    #pragma unroll
    for (int nj = 0; nj < 4; nj++) {
      const int cc = tn * 128 + wc * 64 + nj * 16 + (lane & 15);
      const int lg = cc >> 3;
      #pragma unroll
      for (int v = 0; v < 4; v++) {
        const int rr = tm * 128 + wr * 64 + mi * 16 + (lane >> 4) * 4 + v;
        Cb[(size_t)(rr + 2 * lg) * NN + cc] = f2bf(1.0f - acc[mi][nj][v]);
      }
    }

  // column-sum partials (for neg LSE)
  #pragma unroll
  for (int nj = 0; nj < 4; nj++) {
    const int cc = tn * 128 + wc * 64 + nj * 16 + (lane & 15);
    float s = 0.f;
    #pragma unroll
    for (int mi = 0; mi < 4; mi++)
      #pragma unroll
      for (int v = 0; v < 4; v++) s += 1.0f - acc[mi][nj][v];
    s += __shfl_xor(s, 16, 64);
    s += __shfl_xor(s, 32, 64);
    if (lane < 16) atomicAdd(&colsum[b * 512 + cc], s);
  }
}

// ---------------- Kernel 3: DTW forward (R8 verbatim) + in-wave backtrack ----------------
// 64 blocks x 1 wave. Forward loop is R8's PASSED kernel unchanged: 8-slot x
// 2-row register ring (SGPR-saddr asm loads), uniform vmcnt(14) (loads only),
// prefix-scan STEP with MASKED state updates (garbage from unwritten skew pad
// cells is discarded by the valid mask -> deterministic, R13-proven without
// pad_zero), dec words to LDS (dump slot for invalid). Then, instead of
// dumping dec to global, the same wave runs the epilogue (R14-proven merge):
// neg LSE from GEMM's colsum, lane-0 backtrack with R8's exact walk over LDS
// dec, colpos accumulation, pos LSE, out[b].
// LDS: dec u32[256][64] 64KB | dump [65536,65792) | rlo 65792 | rhi 66816 |
//      colpos 67840 | total 69888 B.
__global__ __launch_bounds__(64, 1) void dtw_fwdbt_kernel(
    const uint16_t* __restrict__ skew, const float* __restrict__ colsum,
    float* __restrict__ out)
{
  extern __shared__ char lds_raw[];
  const int l = threadIdx.x;
  const int b = blockIdx.x;
  const uint16_t* csk = skew + (size_t)b * TT_SKEW * NN;
  const uint64_t base = (uint64_t)(uintptr_t)csk;
  const bool is0 = (l == 0);
  const uint32_t voff_base = 16u * (uint32_t)l;
  const uint32_t dump_addr = 65536u + (((uint32_t)l) << 2);

  uint4v ringA[8], ringB[8];     // rows 2t (A) and 2t+1 (B)
  #pragma unroll
  for (int i = 0; i < 8; ++i) {
    const uint32_t voA = voff_base + ((uint32_t)(2 * i) << 10);
    const uint32_t voB = voA + 1024u;
    asm volatile("global_load_dwordx4 %0, %1, %2" : "=v"(ringA[i]) : "v"(voA), "s"(base));
    asm volatile("global_load_dwordx4 %0, %1, %2" : "=v"(ringB[i]) : "v"(voB), "s"(base));
  }

  float tp[8];
  #pragma unroll
  for (int c = 0; c < 8; ++c) tp[c] = FINF;
  float cl0 = FINF, cl1 = FINF, carry = FINF;

  for (int t0 = 0; t0 < 320; t0 += 8) {
    #pragma unroll
    for (int u = 0; u < 8; ++u) {
      const int t = t0 + u;
      float shA = __shfl_up(cl0, 1, 64);   // tc[r0][8l-1]
      float shB = __shfl_up(cl1, 1, 64);   // tc[r1][8l-1]
      if (is0) { shA = (t == 0) ? 0.0f : FINF; shB = FINF; }
      const float sh_p0 = carry;            // tc[r0-1][8l-1]
      carry = shB;
      const float shA1 = is0 ? FINF : shA;  // row1 diag col0 (INF at l=0)

      asm volatile("s_waitcnt vmcnt(14)" : "+v"(ringA[u]), "+v"(ringB[u]));
      const uint4v A = ringA[u];
      const uint4v Bv = ringB[u];

      const uint32_t rlane = (uint32_t)(t - l);
      const bool valid = rlane < 256u;

      // unpack both rows + prefix sums
      float ca[8], cbv[8], S0[8], S1[8];
      #pragma unroll
      for (int k = 0; k < 4; ++k) {
        ca[2*k]   = __uint_as_float(A[k] << 16);
        ca[2*k+1] = __uint_as_float(A[k] & 0xFFFF0000u);
        cbv[2*k]   = __uint_as_float(Bv[k] << 16);
        cbv[2*k+1] = __uint_as_float(Bv[k] & 0xFFFF0000u);
      }
      S0[0] = ca[0]; S1[0] = cbv[0];
      #pragma unroll
      for (int c = 1; c < 8; ++c) { S0[c] = S0[c-1] + ca[c]; S1[c] = S1[c-1] + cbv[c]; }

      // ---- row 0 ----
      float dcp0[8], mu0[8], w0[8], PW0[8], tn0[8];
      dcp0[0] = sh_p0;
      #pragma unroll
      for (int c = 1; c < 8; ++c) dcp0[c] = tp[c-1];
      #pragma unroll
      for (int c = 0; c < 8; ++c) mu0[c] = fminf(dcp0[c], tp[c]);
      w0[0] = mu0[0];
      #pragma unroll
      for (int c = 1; c < 8; ++c) w0[c] = mu0[c] - S0[c-1];
      PW0[0] = w0[0];
      #pragma unroll
      for (int c = 1; c < 8; ++c) PW0[c] = fminf(PW0[c-1], w0[c]);
      #pragma unroll
      for (int c = 0; c < 8; ++c) tn0[c] = fminf(PW0[c], shA) + S0[c];

      // ---- row 1 (chains on row 0 in-lane) ----
      float dcp1[8], mu1[8], w1[8], PW1[8], tn1[8];
      dcp1[0] = shA1;
      #pragma unroll
      for (int c = 1; c < 8; ++c) dcp1[c] = tn0[c-1];
      #pragma unroll
      for (int c = 0; c < 8; ++c) mu1[c] = fminf(dcp1[c], tn0[c]);
      w1[0] = mu1[0];
      #pragma unroll
      for (int c = 1; c < 8; ++c) w1[c] = mu1[c] - S1[c-1];
      PW1[0] = w1[0];
      #pragma unroll
      for (int c = 1; c < 8; ++c) PW1[c] = fminf(PW1[c-1], w1[c]);
      #pragma unroll
      for (int c = 0; c < 8; ++c) tn1[c] = fminf(PW1[c], shB) + S1[c];

      // ---- decisions (ref tie-break diag > up > left): dd=(lc<mu)?2:(up<dcp) ----
      uint32_t word = 0;
      {
        float lc0[8], lc1[8];
        lc0[0] = shA; lc1[0] = shB;
        #pragma unroll
        for (int c = 1; c < 8; ++c) { lc0[c] = tn0[c-1]; lc1[c] = tn1[c-1]; }
        #pragma unroll
        for (int c = 0; c < 8; ++c) {
          const uint32_t e0 = (tp[c] < dcp0[c]) ? 1u : 0u;
          const uint32_t d0 = (lc0[c] < mu0[c]) ? 2u : e0;
          const uint32_t e1 = (tn0[c] < dcp1[c]) ? 1u : 0u;
          const uint32_t d1 = (lc1[c] < mu1[c]) ? 2u : e1;
          word |= (d0 << (2 * c)) | (d1 << (16 + 2 * c));
        }
      }
      const uint32_t waddr = valid ? ((rlane << 8) + (((uint32_t)l) << 2)) : dump_addr;
      *(uint32_t*)(lds_raw + waddr) = word;

      #pragma unroll
      for (int c = 0; c < 8; ++c) tp[c] = valid ? tn1[c] : tp[c];
      cl0 = valid ? tn0[7] : cl0;
      cl1 = tp[7];

      // refill rows 2(t+8), 2(t+8)+1 (clamped; keeps exactly 16 in flight)
      {
        int rr = 2 * (t + 8); if (rr > 638) rr = 638;
        const uint32_t voA = voff_base + ((uint32_t)rr << 10);
        const uint32_t voB = voA + 1024u;
        asm volatile("global_load_dwordx4 %0, %1, %2" : "=v"(ringA[u]) : "v"(voA), "s"(base));
        asm volatile("global_load_dwordx4 %0, %1, %2" : "=v"(ringB[u]) : "v"(voB), "s"(base));
      }
    }
  }
  asm volatile("s_waitcnt vmcnt(0)" ::: "memory");
  __syncthreads();

  // ---------------- in-wave epilogue (R14-proven merge pattern) ----------------
  uint16_t* rlo    = (uint16_t*)(lds_raw + 65792);
  uint16_t* rhi    = (uint16_t*)(lds_raw + 66816);
  float*    colpos = (float*)  (lds_raw + 67840);
  const uint32_t* dec32 = (const uint32_t*)lds_raw;

  for (int r = l; r < NN; r += 64) { rlo[r] = 1; rhi[r] = 0; colpos[r] = 0.0f; }

  // ---- neg = LSE over colsum[b][0..511] (computed by GEMM epilogue) ----
  const float* cs = colsum + (size_t)b * 512;
  float nv[8];
  float m = -FINF;
  #pragma unroll
  for (int k = 0; k < 8; ++k) { nv[k] = cs[l + 64 * k]; m = fmaxf(m, nv[k]); }
  #pragma unroll
  for (int d = 1; d < 64; d <<= 1) m = fmaxf(m, __shfl_xor(m, d, 64));
  float e = 0.f;
  #pragma unroll
  for (int k = 0; k < 8; ++k) e += expf(nv[k] - m);
  #pragma unroll
  for (int d = 1; d < 64; d <<= 1) e += __shfl_xor(e, d, 64);
  const float neg = m + logf(e);
  __syncthreads();

  // ---- backtrack (lane 0): R8's exact walk over the LDS dec array ----
  if (l == 0) {
    int i = NN - 1, j = NN - 1, hicur = NN - 1;
    int cidx = -1; uint32_t cw = 0;
    while (i > 0 && j > 0) {
      const int widx = (i >> 1) * 64 + (j >> 3);
      if (widx != cidx) { cw = dec32[widx]; cidx = widx; }
      const uint32_t dd = (cw >> (((i & 1) << 4) + ((j & 7) << 1))) & 3u;
      if (dd == 2u) { j--; }           // left: stay in row
      else {
        rlo[i] = (uint16_t)j; rhi[i] = (uint16_t)hicur;  // leave row i
        i--;
        if (dd == 0u) j--;             // diag also moves left
        hicur = j;                     // entry column of new row
      }
    }
    rlo[i] = (uint16_t)j; rhi[i] = (uint16_t)hicur;      // pending row at exit
  }
  __syncthreads();

  // ---- colpos: 8 rows per lane (2-row skew addressing) ----
  for (int r = l; r < NN; r += 64) {
    const int lo = rlo[r], hi = rhi[r];
    for (int j = lo; j <= hi; j++) {
      const float cv = bf2f(csk[(size_t)(r + 2 * (j >> 3)) * NN + j]);
      atomicAdd(&colpos[j], cv);
    }
  }
  if (l == 0 && rlo[0] != 0) atomicAdd(&colpos[0], bf2f(csk[0]));
  __syncthreads();

  // ---- pos = LSE over colpos[512] ----
  float mv[8];
  float mx2 = -FINF;
  #pragma unroll
  for (int k = 0; k < 8; k++) { mv[k] = colpos[l + 64 * k]; mx2 = fmaxf(mx2, mv[k]); }
  #pragma unroll
  for (int d = 1; d < 64; d <<= 1) mx2 = fmaxf(mx2, __shfl_xor(mx2, d, 64));
  float se2 = 0.f;
  #pragma unroll
  for (int k = 0; k < 8; k++) se2 += expf(mv[k] - mx2);
  #pragma unroll
  for (int d = 1; d < 64; d <<= 1) se2 += __shfl_xor(se2, d, 64);
  const float pos = mx2 + logf(se2);

  if (l == 0) out[b] = pos - neg;
}

extern "C" void kernel_launch(void* const* d_in, const int* in_sizes, int n_in,
                              void* d_out, int out_size, void* d_ws, size_t ws_size,
                              hipStream_t stream)
{
  (void)in_sizes; (void)n_in; (void)out_size; (void)ws_size;
  const float* x = (const float*)d_in[0];
  const float* y = (const float*)d_in[1];
  float* out = (float*)d_out;
  char* ws = (char*)d_ws;
  uint16_t* xnb   = (uint16_t*)ws;
  uint16_t* ynb   = (uint16_t*)(ws + (size_t)16777216);
  uint16_t* skew  = (uint16_t*)(ws + (size_t)33554432);
  float*   colsum = (float*)   (ws + (size_t)75497472);

  (void)hipFuncSetAttribute((const void*)dtw_fwdbt_kernel,
                            hipFuncAttributeMaxDynamicSharedMemorySize, 69888);

  zero_colsum_kernel<<<128, 256, 0, stream>>>(colsum);
  norm_cast_kernel<<<16384, 256, 0, stream>>>(x, y, xnb, ynb);
  gemm_cost_kernel<<<1024, 256, 0, stream>>>(xnb, ynb, skew, colsum);
  dtw_fwdbt_kernel<<<64, 64, 69888, stream>>>(skew, colsum, out);
}